// Round 1
// 290.289 us; speedup vs baseline: 1.0468x; 1.0468x over previous
//
#include <hip/hip_runtime.h>
#include <cstdint>
#include <cstddef>

#define NB 64
#define NN 2048
#define ND 128
#define NK 1024
#define NTOT (NB * NN)        // 131072
#define EPG (NN * 32)         // 65536 edges per graph
#define EPG4 (EPG / 4)        // 16384 int4 per graph
#define P 8                   // slices per graph
#define SLICE4 (EPG4 / P)     // 2048 int4 per slice
#define PROJ_BLOCKS (NTOT / 8)   // 16384: 8 nodes/block (32 lanes per node, float4)
#define HIST_BLOCKS (NB * P)     // 512
#define FULL4 (NTOT * 32)        // float4 count of out_full = 4194304
#define DIST4 (2 * NB * NK * 32) // float4 count of dist|com = 4194304

// ---------------- fused: s = feature @ W  +  per-slice degree histograms ----------------
__global__ __launch_bounds__(256) void k_proj_hist(
    const float* __restrict__ feat, const float* __restrict__ W, float* __restrict__ s,
    const int4* __restrict__ src4, const int4* __restrict__ dst4,
    unsigned* __restrict__ part_o, unsigned* __restrict__ part_i) {
    __shared__ unsigned ho[NN];
    __shared__ unsigned hi2[NN];
    int tid = threadIdx.x;
    if (blockIdx.x < PROJ_BLOCKS) {
        // projection: 32 lanes per node, 16 B/lane
        int node = blockIdx.x * 8 + (tid >> 5);
        int l = tid & 31;
        float4 v = ((const float4*)feat)[(size_t)node * 32 + l];
        float4 w = ((const float4*)W)[l];
        float val = v.x * w.x + v.y * w.y + v.z * w.z + v.w * w.w;
        #pragma unroll
        for (int off = 16; off > 0; off >>= 1) val += __shfl_down(val, off);
        if (l == 0) s[node] = val;
        return;
    }
    int blk = blockIdx.x - PROJ_BLOCKS;
    for (int j = tid; j < NN; j += 256) { ho[j] = 0u; hi2[j] = 0u; }
    __syncthreads();
    const int4* sp = src4 + (size_t)blk * SLICE4;
    const int4* dp = dst4 + (size_t)blk * SLICE4;
    for (int i = tid; i < SLICE4; i += 256) {
        int4 a = sp[i];
        int4 b = dp[i];
        atomicAdd(&ho[a.x & (NN - 1)], 1u); atomicAdd(&ho[a.y & (NN - 1)], 1u);
        atomicAdd(&ho[a.z & (NN - 1)], 1u); atomicAdd(&ho[a.w & (NN - 1)], 1u);
        atomicAdd(&hi2[b.x & (NN - 1)], 1u); atomicAdd(&hi2[b.y & (NN - 1)], 1u);
        atomicAdd(&hi2[b.z & (NN - 1)], 1u); atomicAdd(&hi2[b.w & (NN - 1)], 1u);
    }
    __syncthreads();
    unsigned* po = part_o + (size_t)blk * NN;
    unsigned* pi = part_i + (size_t)blk * NN;
    for (int j = tid; j < NN; j += 256) { po[j] = ho[j]; pi[j] = hi2[j]; }
}

// ---------------- per-slice scatter; m computed in-block from s & part_o ----------------
__global__ __launch_bounds__(256) void k_scatter(
    const int4* __restrict__ src4, const int4* __restrict__ dst4,
    const float* __restrict__ s, const unsigned* __restrict__ part_o,
    float* __restrict__ part_a) {
    __shared__ float ms[NN];
    __shared__ float acc[NN];
    int blk = blockIdx.x, tid = threadIdx.x;
    int g = blk >> 3;   // blk / P
    for (int j = tid; j < NN; j += 256) {
        const unsigned* po = part_o + (size_t)g * P * NN + j;
        unsigned od = 0;
        #pragma unroll
        for (int p = 0; p < P; p++) od += po[(size_t)p * NN];
        ms[j] = s[g * NN + j] * rsqrtf(fmaxf((float)od, 1.0f));
        acc[j] = 0.0f;
    }
    __syncthreads();
    const int4* sp = src4 + (size_t)blk * SLICE4;
    const int4* dp = dst4 + (size_t)blk * SLICE4;
    for (int i = tid; i < SLICE4; i += 256) {
        int4 a = sp[i];
        int4 b = dp[i];
        atomicAdd(&acc[b.x & (NN - 1)], ms[a.x & (NN - 1)]);
        atomicAdd(&acc[b.y & (NN - 1)], ms[a.y & (NN - 1)]);
        atomicAdd(&acc[b.z & (NN - 1)], ms[a.z & (NN - 1)]);
        atomicAdd(&acc[b.w & (NN - 1)], ms[a.w & (NN - 1)]);
    }
    __syncthreads();
    float* pa = part_a + (size_t)blk * NN;
    for (int j = tid; j < NN; j += 256) pa[j] = acc[j];
}

// ---------------- reduce partials -> score, t, expsum (full-width) ----------------
__global__ __launch_bounds__(256) void k_score(
    const float* __restrict__ part_a, const unsigned* __restrict__ part_i,
    const float* __restrict__ bptr, float* __restrict__ score,
    float* __restrict__ t, float* __restrict__ expsum) {
    __shared__ float ws[4];
    int node = blockIdx.x * 256 + threadIdx.x;
    int g = node >> 11, local = node & (NN - 1);
    const float* pa = part_a + (size_t)g * P * NN + local;
    const unsigned* pi = part_i + (size_t)g * P * NN + local;
    float a = 0.0f; unsigned id2 = 0;
    #pragma unroll
    for (int p = 0; p < P; p++) { a += pa[(size_t)p * NN]; id2 += pi[(size_t)p * NN]; }
    float sc = a * rsqrtf(fmaxf((float)id2, 1.0f)) + bptr[0];
    score[node] = sc;
    t[node] = tanhf(sc);
    float e = expf(sc);
    #pragma unroll
    for (int off = 32; off > 0; off >>= 1) e += __shfl_down(e, off);
    if ((threadIdx.x & 63) == 0) ws[threadIdx.x >> 6] = e;
    __syncthreads();
    if (threadIdx.x == 0) atomicAdd(expsum, ws[0] + ws[1] + ws[2] + ws[3]);
}

// ---------------- fused: blocks 0..63 sort one graph each; blocks 64+ emit out_full ----------------
__global__ __launch_bounds__(1024) void k_sortemit(
    const float* __restrict__ score, const float* __restrict__ t,
    const float4* __restrict__ feat4, float4* __restrict__ out_full4,
    float* __restrict__ perm_f, float* __restrict__ permc_f) {
    __shared__ unsigned long long key[NN];
    __shared__ unsigned msk[NN / 32];   // 64 words: selected-node bitmask
    __shared__ unsigned exz[NN / 32];   // exclusive prefix of zero-counts
    int tid = threadIdx.x;
    if (blockIdx.x >= NB) {
        size_t i = (size_t)(blockIdx.x - NB) * 1024 + tid;   // < FULL4
        int row = (int)(i >> 5);
        float tv = t[row];
        float4 v = feat4[i];
        out_full4[i] = make_float4(v.x * tv, v.y * tv, v.z * tv, v.w * tv);
        return;
    }
    int g = blockIdx.x;
    for (int j = tid; j < NN; j += 1024) {
        float sc = score[g * NN + j];
        unsigned u  = __float_as_uint(sc);
        unsigned ok = (u & 0x80000000u) ? ~u : (u | 0x80000000u);  // order-preserving
        key[j] = ((unsigned long long)(~ok) << 32) | (unsigned)j;  // asc key == desc score, asc idx
    }
    if (tid < NN / 32) msk[tid] = 0u;
    __syncthreads();

    // bitonic sort of 2048 keys ascending
    for (unsigned k = 2; k <= NN; k <<= 1) {
        for (unsigned j = k >> 1; j > 0; j >>= 1) {
            for (unsigned t2 = tid; t2 < NN; t2 += 1024) {
                unsigned ixj = t2 ^ j;
                if (ixj > t2) {
                    bool up = ((t2 & k) == 0);
                    unsigned long long x = key[t2], y = key[ixj];
                    bool sw = up ? (x > y) : (x < y);
                    if (sw) { key[t2] = y; key[ixj] = x; }
                }
            }
            __syncthreads();
        }
    }

    // top half -> perm; mark membership bits
    unsigned local = (unsigned)(key[tid] & 0xFFFFFFFFu);
    perm_f[g * NK + tid] = (float)(g * NN + (int)local);
    atomicOr(&msk[local >> 5], 1u << (local & 31));
    __syncthreads();

    // complement = unselected ids ascending, via rank compaction (replaces 55-pass bitonic)
    if (tid < NN / 32) {
        unsigned zc = 32u - (unsigned)__popc(msk[tid]);
        unsigned v = zc;
        #pragma unroll
        for (int off = 1; off < 64; off <<= 1) {
            unsigned o = __shfl_up(v, off);
            if (tid >= off) v += o;
        }
        exz[tid] = v - zc;   // exclusive scan
    }
    __syncthreads();
    for (int j = tid; j < NN; j += 1024) {
        unsigned w = msk[j >> 5];
        if (!((w >> (j & 31)) & 1u)) {
            unsigned pos = exz[j >> 5] + (unsigned)__popc(~w & ((1u << (j & 31)) - 1u));
            permc_f[g * NK + pos] = (float)(g * NN + j);
        }
    }
}

// ---------------- gather-based dist|com emit + softmax tail ----------------
__global__ __launch_bounds__(1024) void k_distcom(
    const float4* __restrict__ feat4, const float* __restrict__ t,
    const float* __restrict__ perm_all, float4* __restrict__ out_dist4,
    const float* __restrict__ score, const float* __restrict__ expsum,
    float* __restrict__ out_sm) {
    size_t i = (size_t)blockIdx.x * 1024 + threadIdx.x;
    if (i < (size_t)DIST4) {
        int orow = (int)(i >> 5), col = (int)(i & 31);
        int srow = (int)perm_all[orow];          // perm|permc contiguous, values are exact ints
        float tv = t[srow];
        float4 v = feat4[(size_t)srow * 32 + col];
        out_dist4[i] = make_float4(v.x * tv, v.y * tv, v.z * tv, v.w * tv);
    } else {
        size_t j = i - (size_t)DIST4;
        if (j < NTOT) out_sm[j] = expf(score[j]) / expsum[0];
    }
}

extern "C" void kernel_launch(void* const* d_in, const int* in_sizes, int n_in,
                              void* d_out, int out_size, void* d_ws, size_t ws_size,
                              hipStream_t stream) {
    const float* feat = (const float*)d_in[0];
    const float* W    = (const float*)d_in[1];
    const float* b    = (const float*)d_in[2];
    const int*   src  = (const int*)d_in[3];
    const int*   dst  = (const int*)d_in[4];
    float* out = (float*)d_out;

    // workspace layout
    float* expsum = (float*)d_ws;                    // 64 (pad)
    float* s      = expsum + 64;                     // NTOT
    float* score  = s + NTOT;                        // NTOT
    float* t      = score + NTOT;                    // NTOT
    unsigned* part_o = (unsigned*)(t + NTOT);        // NB*P*NN = 1M
    unsigned* part_i = part_o + (size_t)NB * P * NN; // 1M
    float* part_a    = (float*)(part_i + (size_t)NB * P * NN); // 1M

    // output layout (floats)
    float* out_dist  = out;                           // NB*NK*ND dist | NB*NK*ND com (contiguous)
    float* out_full  = out + 2 * (size_t)NB * NK * ND;
    float* out_perm  = out_full + (size_t)NTOT * ND;  // NB*NK
    float* out_permc = out_perm + NB * NK;            // NB*NK (contiguous after perm)
    float* out_sm    = out_permc + NB * NK;           // NTOT

    hipMemsetAsync(expsum, 0, 64 * sizeof(float), stream);

    k_proj_hist<<<PROJ_BLOCKS + HIST_BLOCKS, 256, 0, stream>>>(
        feat, W, s, (const int4*)src, (const int4*)dst, part_o, part_i);
    k_scatter<<<NB * P, 256, 0, stream>>>((const int4*)src, (const int4*)dst, s, part_o, part_a);
    k_score<<<NTOT / 256, 256, 0, stream>>>(part_a, part_i, b, score, t, expsum);
    k_sortemit<<<NB + FULL4 / 1024, 1024, 0, stream>>>(
        score, t, (const float4*)feat, (float4*)out_full, out_perm, out_permc);
    k_distcom<<<(DIST4 + NTOT + 1023) / 1024, 1024, 0, stream>>>(
        (const float4*)feat, t, out_perm, (float4*)out_dist, score, expsum, out_sm);
}